// Round 13
// baseline (597.820 us; speedup 1.0000x reference)
//
#include <hip/hip_runtime.h>
#include <hip/hip_fp16.h>

#define HIDDEN 128
#define BSHIFT 8          // bucket = 256 destination nodes
#define BMASK 255
#define CHUNK 4096        // edges per fill_bin block (40 KB LDS -> 4 blocks/CU)
#define BCAP 6144         // per-bucket capacity in ptmp (mean 4096, 32 sigma)

// Feature buffers are SLICE-MAJOR: H[(s*N + node)*16 + c], s in [0,8), c in [0,16).
// Slice s is processed by blocks with (blockIdx&7)==s -> XCD s (round-robin
// dispatch), so each XCD's gather working set is 3.2 MB < 4 MB L2.

typedef _Float16 h8 __attribute__((ext_vector_type(8)));
typedef float f4x __attribute__((ext_vector_type(4)));

// ----------------- fill pass 1: LDS-bin edges into bucket-strided temp array
__global__ __launch_bounds__(256) void fill_bin(const int* __restrict__ row,
                                                const int* __restrict__ col,
                                                int* __restrict__ bcnt,
                                                int2* __restrict__ ptmp, int E) {
    __shared__ int cnt[512], start[512], place[512], gbase[512];
    __shared__ int ssum[256];
    __shared__ int2 stage[CHUNK];
    int t = threadIdx.x;
    int e0 = blockIdx.x * CHUNK;
    int e1 = min(e0 + CHUNK, E);
    cnt[t] = 0; cnt[t + 256] = 0;
    __syncthreads();
    for (int e = e0 + t; e < e1; e += 256)
        atomicAdd(&cnt[col[e] >> BSHIFT], 1);
    __syncthreads();
    int s2 = cnt[2 * t] + cnt[2 * t + 1];
    ssum[t] = s2;
    __syncthreads();
    for (int d = 1; d < 256; d <<= 1) {
        int v = (t >= d) ? ssum[t - d] : 0;
        __syncthreads();
        ssum[t] += v;
        __syncthreads();
    }
    int excl = ssum[t] - s2;
    start[2 * t] = excl;
    start[2 * t + 1] = excl + cnt[2 * t];
    place[2 * t] = excl;
    place[2 * t + 1] = excl + cnt[2 * t];
    __syncthreads();
    for (int e = e0 + t; e < e1; e += 256) {
        int c = col[e], r = row[e];
        int slot = atomicAdd(&place[c >> BSHIFT], 1);
        stage[slot] = make_int2(r, c);
    }
    {
        int c0 = cnt[t], c1 = cnt[t + 256];
        if (c0 > 0) gbase[t] = atomicAdd(&bcnt[t], c0);
        if (c1 > 0) gbase[t + 256] = atomicAdd(&bcnt[t + 256], c1);
    }
    __syncthreads();
    int n = e1 - e0;
    for (int i = t; i < n; i += 256) {
        int2 p = stage[i];
        int b = p.y >> BSHIFT;
        ptmp[(size_t)b * BCAP + gbase[b] + (i - start[b])] = p;
    }
}

// --------------- tiny single-block scan of bucket totals -> global CSR bases
__global__ __launch_bounds__(512) void scan_buckets(const int* __restrict__ bcnt,
                                                    int* __restrict__ bbase, int NB) {
    __shared__ int s[512];
    int t = threadIdx.x;
    int v0 = (t < NB) ? bcnt[t] : 0;
    s[t] = v0;
    __syncthreads();
    for (int d = 1; d < 512; d <<= 1) {
        int v = (t >= d) ? s[t - d] : 0;
        __syncthreads();
        s[t] += v;
        __syncthreads();
    }
    bbase[t] = s[t] - v0;   // exclusive prefix
}

// ---- fill pass 2: one block per bucket — LDS degree histogram + local scatter
// also pads this bucket's x rows into dinv-folded fp16 xp (fused pad_x)
__global__ __launch_bounds__(256) void fill_scatter(const int2* __restrict__ ptmp,
                                                    const int* __restrict__ bcnt,
                                                    const int* __restrict__ bbase,
                                                    const float* __restrict__ x,
                                                    int* __restrict__ offsets,
                                                    float* __restrict__ dinv,
                                                    int* __restrict__ sorted_r,
                                                    __half* __restrict__ xp,
                                                    int N, int E) {
    __shared__ int2 stage[BCAP];               // 48 KB
    __shared__ int cnt[256], loff[256], cur[256];
    int b = blockIdx.x, t = threadIdx.x;
    int m = bcnt[b];
    int base = bbase[b];
    int nbase = b << BSHIFT;
    cnt[t] = 0;
    __syncthreads();
    for (int i = t; i < m; i += 256) {
        int2 p = ptmp[(size_t)b * BCAP + i];
        stage[i] = p;
        atomicAdd(&cnt[p.y & BMASK], 1);
    }
    __syncthreads();
    int my = cnt[t];
    loff[t] = my;
    __syncthreads();
    for (int d = 1; d < 256; d <<= 1) {
        int v = (t >= d) ? loff[t - d] : 0;
        __syncthreads();
        loff[t] += v;
        __syncthreads();
    }
    int excl = loff[t] - my;
    cur[t] = excl;
    int node = nbase + t;
    float dv = rsqrtf((float)(my + 1));
    if (node < N) {
        offsets[node] = base + excl;
        dinv[node] = dv;
        __half hrow[16];
#pragma unroll
        for (int c = 0; c < 11; ++c)
            hrow[c] = __float2half(x[(size_t)node * 11 + c] * dv);
#pragma unroll
        for (int c = 11; c < 16; ++c) hrow[c] = __float2half(0.f);
        *(uint4*)(xp + (size_t)node * 16)     = *(uint4*)hrow;
        *(uint4*)(xp + (size_t)node * 16 + 8) = *(uint4*)(hrow + 8);
    }
    if (b == gridDim.x - 1 && t == 0) offsets[N] = E;
    __syncthreads();
    for (int i = t; i < m; i += 256) {
        int2 p = stage[i];
        int slot = atomicAdd(&cur[p.y & BMASK], 1);
        sorted_r[base + slot] = p.x;   // contiguous ~16 KB region, block-local
    }
}

// ------ agg16 + input GEMM fused: writes layer-1 H in SLICE-MAJOR fp16
__global__ __launch_bounds__(256) void agg16_fused(const __half* __restrict__ xp,
                                                   const float* __restrict__ W1,
                                                   const int* __restrict__ offsets,
                                                   const int* __restrict__ sorted_r,
                                                   const float* __restrict__ dinv,
                                                   __half* __restrict__ out, int N) {
    __shared__ float W1s[11 * 128];   // 5.6 KB
    __shared__ float arow[4][16];
    int t = threadIdx.x;
    for (int q = t; q < 11 * 128; q += 256) W1s[q] = W1[q];
    int wv = t >> 6, lane = t & 63;
    int c = blockIdx.x * 4 + wv;
    bool valid = c < N;
    int g = lane >> 3, cp = lane & 7;
    const __half2* xp2 = (const __half2*)xp;
    float ax = 0.f, ay = 0.f;
    if (valid) {
        int beg = offsets[c], end = offsets[c + 1];
        if (g == 0) {
            float2 v = __half22float2(xp2[(size_t)c * 8 + cp]);   // self (dc folded)
            ax = v.x; ay = v.y;
        }
        int i = beg;
        for (; i + 16 <= end; i += 16) {
            int r0 = sorted_r[i + g];
            int r1 = sorted_r[i + g + 8];
            float2 v0 = __half22float2(xp2[(size_t)r0 * 8 + cp]);
            float2 v1 = __half22float2(xp2[(size_t)r1 * 8 + cp]);
            ax += v0.x + v1.x; ay += v0.y + v1.y;
        }
        if (i < end) {                       // predicated batch tail
            int last = end - 1;
            int i0 = i + g, i1 = i + g + 8;
            int r0 = sorted_r[min(i0, last)];
            int r1 = sorted_r[min(i1, last)];
            float2 v0 = __half22float2(xp2[(size_t)r0 * 8 + cp]);
            float2 v1 = __half22float2(xp2[(size_t)r1 * 8 + cp]);
            if (i0 <= last) { ax += v0.x; ay += v0.y; }
            if (i1 <= last) { ax += v1.x; ay += v1.y; }
        }
    }
    ax += __shfl_xor(ax, 32); ay += __shfl_xor(ay, 32);
    ax += __shfl_xor(ax, 16); ay += __shfl_xor(ay, 16);
    ax += __shfl_xor(ax, 8);  ay += __shfl_xor(ay, 8);
    if (valid && lane < 8) {
        float dc = dinv[c];
        arow[wv][cp * 2]     = ax * dc;
        arow[wv][cp * 2 + 1] = ay * dc;
    }
    __syncthreads();
    // block GEMM: 4 nodes x 128 ch, slice-major output
    int j = t & 127, half = t >> 7;
#pragma unroll
    for (int nn = 0; nn < 2; ++nn) {
        int n = half * 2 + nn;
        int node = blockIdx.x * 4 + n;
        if (node < N) {
            float acc = 0.f;
#pragma unroll
            for (int cc = 0; cc < 11; ++cc) acc += arow[n][cc] * W1s[cc * 128 + j];
            out[((size_t)(j >> 4) * N + node) * 16 + (j & 15)] = __float2half(acc);
        }
    }
}

// ---------------- pack W [128][128] fp32 -> MFMA fragment order, hi|lo fp16
__global__ __launch_bounds__(256) void pack_w(const float* __restrict__ W,
                                              const float* __restrict__ bias,
                                              __half* __restrict__ packed) {
    int q = blockIdx.x * 256 + threadIdx.x;
    if (q < 2048) {
        int s = q >> 9, rem = q & 511, ct = rem >> 6, l = rem & 63;
        int b = l >> 4, n = l & 15;
        __half hi8[8], lo8[8];
#pragma unroll
        for (int i = 0; i < 8; ++i) {
            float w = W[(s * 32 + b * 8 + i) * HIDDEN + ct * 16 + n];
            __half h = __float2half(w);
            hi8[i] = h;
            lo8[i] = __float2half(w - __half2float(h));
        }
        *(uint4*)(packed + (size_t)q * 8)         = *(uint4*)hi8;
        *(uint4*)(packed + 16384 + (size_t)q * 8) = *(uint4*)lo8;
    }
    if (q < 128) packed[32768 + q] = __float2half(bias[q]);
}

// ---- MFMA GEMM, register-resident W; slice-major in/out
__global__ __launch_bounds__(256, 2) void gemm_mfma(const __half* __restrict__ H,
                                                    const __half* __restrict__ packed,
                                                    const float* __restrict__ dinv,
                                                    __half* __restrict__ out,
                                                    int N, int ngroups) {
    int l = threadIdx.x & 63, wv = threadIdx.x >> 6;
    int cthalf = wv & 1;
    int n16 = l & 15, koct = l >> 4;
    h8 whi[4][4], wlo[4][4];
#pragma unroll
    for (int s = 0; s < 4; ++s)
#pragma unroll
        for (int mt = 0; mt < 4; ++mt) {
            int ct = cthalf * 4 + mt;
            whi[s][mt] = *(const h8*)(packed + (size_t)((s * 8 + ct) * 64 + l) * 8);
            wlo[s][mt] = *(const h8*)(packed + 16384 + (size_t)((s * 8 + ct) * 64 + l) * 8);
        }
    h8 biasf[4];
    const __half* bias_h = packed + 32768;
#pragma unroll
    for (int s = 0; s < 4; ++s)
        biasf[s] = *(const h8*)(bias_h + s * 32 + koct * 8);

    int lsl = koct >> 1, lc0 = (koct & 1) * 8;   // load slice-part / offset

    for (int g = blockIdx.x * 2 + (wv >> 1); g < ngroups; g += gridDim.x * 2) {
        int node = g * 16 + n16;
        bool ok = node < N;
        f4x acc[4];
#pragma unroll
        for (int mt = 0; mt < 4; ++mt) acc[mt] = (f4x){0.f, 0.f, 0.f, 0.f};
#pragma unroll
        for (int s = 0; s < 4; ++s) {
            uint4 bv = make_uint4(0u, 0u, 0u, 0u);
            if (ok) {
                int sl = 2 * s + lsl;   // slice of channels k = s*32 + koct*8
                bv = *(const uint4*)(H + ((size_t)sl * N + node) * 16 + lc0);
            }
            __half2* bh2 = (__half2*)&bv;
            const __half2* bb = (const __half2*)&biasf[s];
#pragma unroll
            for (int p = 0; p < 4; ++p) {
                float2 f  = __half22float2(bh2[p]);
                float2 bf = __half22float2(bb[p]);
                bh2[p] = __floats2half2_rn(fmaxf(f.x + bf.x, 0.f), fmaxf(f.y + bf.y, 0.f));
            }
            h8 bfrag = *(h8*)&bv;
#pragma unroll
            for (int mt = 0; mt < 4; ++mt) {
                acc[mt] = __builtin_amdgcn_mfma_f32_16x16x32_f16(whi[s][mt], bfrag, acc[mt], 0, 0, 0);
                acc[mt] = __builtin_amdgcn_mfma_f32_16x16x32_f16(wlo[s][mt], bfrag, acc[mt], 0, 0, 0);
            }
        }
        if (ok) {
            float dv = dinv[node];
#pragma unroll
            for (int mt = 0; mt < 4; ++mt) {
                int sl = cthalf * 4 + mt;            // output slice
                __half2 h01 = __floats2half2_rn(acc[mt][0] * dv, acc[mt][1] * dv);
                __half2 h23 = __floats2half2_rn(acc[mt][2] * dv, acc[mt][3] * dv);
                uint2 o;
                o.x = *(unsigned int*)&h01; o.y = *(unsigned int*)&h23;
                *(uint2*)(out + ((size_t)sl * N + node) * 16 + koct * 4) = o;
            }
        }
    }
}

// -------- channel-sliced aggregation: slice = bid&7 -> XCD-local L2 working set
// wave = 1 node-slice; 16 edge-groups x 4 lanes x uint2 (4 halves)
__global__ __launch_bounds__(256) void agg128h_sliced(const __half* __restrict__ src,
                                                      __half* __restrict__ dst,
                                                      const int* __restrict__ offsets,
                                                      const int* __restrict__ sorted_r,
                                                      const float* __restrict__ dinv,
                                                      int N) {
    int s = blockIdx.x & 7;
    int c = (blockIdx.x >> 3) * 4 + (threadIdx.x >> 6);
    int lane = threadIdx.x & 63;
    if (c >= N) return;
    int g = lane >> 2, sub = lane & 3;
    int beg = offsets[c], end = offsets[c + 1];
    const uint2* sp = (const uint2*)src + (size_t)s * N * 4;   // uint2 = 4 halves
    float a0 = 0.f, a1 = 0.f, a2 = 0.f, a3 = 0.f;
    auto accum = [&](uint2 u) {
        float2 f0 = __half22float2(*(__half2*)&u.x);
        float2 f1 = __half22float2(*(__half2*)&u.y);
        a0 += f0.x; a1 += f0.y; a2 += f1.x; a3 += f1.y;
    };
    if (g == 0) accum(sp[(size_t)c * 4 + sub]);    // self loop (dinv folded)
    int i = beg;
    for (; i + 16 <= end; i += 16) {               // 16 edges per phase
        int r = sorted_r[i + g];
        accum(sp[(size_t)r * 4 + sub]);
    }
    if (i < end) {                                 // predicated batch tail
        int last = end - 1;
        int ii = i + g;
        int r = sorted_r[min(ii, last)];
        uint2 u = sp[(size_t)r * 4 + sub];
        if (ii <= last) accum(u);
    }
    a0 += __shfl_xor(a0, 32); a1 += __shfl_xor(a1, 32);
    a2 += __shfl_xor(a2, 32); a3 += __shfl_xor(a3, 32);
    a0 += __shfl_xor(a0, 16); a1 += __shfl_xor(a1, 16);
    a2 += __shfl_xor(a2, 16); a3 += __shfl_xor(a3, 16);
    a0 += __shfl_xor(a0, 8);  a1 += __shfl_xor(a1, 8);
    a2 += __shfl_xor(a2, 8);  a3 += __shfl_xor(a3, 8);
    a0 += __shfl_xor(a0, 4);  a1 += __shfl_xor(a1, 4);
    a2 += __shfl_xor(a2, 4);  a3 += __shfl_xor(a3, 4);
    if (g == 0) {
        float dc = dinv[c];
        __half2 h01 = __floats2half2_rn(a0 * dc, a1 * dc);
        __half2 h23 = __floats2half2_rn(a2 * dc, a3 * dc);
        uint2 o;
        o.x = *(unsigned int*)&h01; o.y = *(unsigned int*)&h23;
        ((uint2*)dst + (size_t)s * N * 4)[(size_t)c * 4 + sub] = o;
    }
}

// --------------------------------------------- pooling stage 1 (slice-major in)
__global__ __launch_bounds__(256) void pool_partial(const __half* __restrict__ h,
                                                    const int* __restrict__ batch,
                                                    float* __restrict__ partials, int N) {
    int g = blockIdx.x >> 3, part8 = blockIdx.x & 7;
    int t = threadIdx.x, cp = t & 63, rp = t >> 6;
    int lo = 0, hi = N;
    while (lo < hi) { int m = (lo + hi) >> 1; if (batch[m] < g) lo = m + 1; else hi = m; }
    int beg = lo;
    lo = beg; hi = N;
    while (lo < hi) { int m = (lo + hi) >> 1; if (batch[m] < g + 1) lo = m + 1; else hi = m; }
    int end = lo;
    const __half2* h2 = (const __half2*)h;
    size_t sbase = (size_t)(cp >> 3) * N * 8;   // slice of channel-pair cp
    int soff = cp & 7;
    float ax = 0.f, ay = 0.f;
    for (int i = beg + part8 * 4 + rp; i < end; i += 32) {
        float2 v = __half22float2(h2[sbase + (size_t)i * 8 + soff]);
        ax += v.x; ay += v.y;
    }
    __shared__ float px[4][64], py[4][64];
    px[rp][cp] = ax; py[rp][cp] = ay;
    __syncthreads();
    if (rp == 0) {
        float sx = px[0][cp] + px[1][cp] + px[2][cp] + px[3][cp];
        float sy = py[0][cp] + py[1][cp] + py[2][cp] + py[3][cp];
        partials[(size_t)blockIdx.x * 128 + cp * 2]     = sx;
        partials[(size_t)blockIdx.x * 128 + cp * 2 + 1] = sy;
    }
}

// ------------------------------------------------- pooling stage 2 + MLP head
__global__ __launch_bounds__(128) void head_kernel(const float* __restrict__ partials,
                                                   const int* __restrict__ batch,
                                                   const float* __restrict__ b4,
                                                   const float* __restrict__ Wd1,
                                                   const float* __restrict__ bd1,
                                                   const float* __restrict__ Wd2,
                                                   const float* __restrict__ bd2,
                                                   const float* __restrict__ Wo,
                                                   const float* __restrict__ bo,
                                                   float* __restrict__ out, int N) {
    int g = blockIdx.x;
    int j = threadIdx.x;
    __shared__ float sA[128], sB[128], red[128];
    int lo = 0, hi = N;
    while (lo < hi) { int m = (lo + hi) >> 1; if (batch[m] < g) lo = m + 1; else hi = m; }
    int beg = lo;
    lo = beg; hi = N;
    while (lo < hi) { int m = (lo + hi) >> 1; if (batch[m] < g + 1) lo = m + 1; else hi = m; }
    int cnt = lo - beg;
    float s = 0.f;
#pragma unroll
    for (int p = 0; p < 8; ++p) s += partials[(size_t)(g * 8 + p) * 128 + j];
    sA[j] = (cnt > 0) ? s / (float)cnt + b4[j] : 0.f;
    __syncthreads();
    float a = bd1[j];
#pragma unroll 4
    for (int k = 0; k < 128; ++k) a += sA[k] * Wd1[k * HIDDEN + j];
    sB[j] = fmaxf(a, 0.f);
    __syncthreads();
    a = bd2[j];
#pragma unroll 4
    for (int k = 0; k < 128; ++k) a += sB[k] * Wd2[k * HIDDEN + j];
    red[j] = fmaxf(a, 0.f) * Wo[j];
    __syncthreads();
    for (int d = 64; d > 0; d >>= 1) {
        if (j < d) red[j] += red[j + d];
        __syncthreads();
    }
    if (j == 0) out[g] = red[0] + bo[0];
}

// ============================================================================
extern "C" void kernel_launch(void* const* d_in, const int* in_sizes, int n_in,
                              void* d_out, int out_size, void* d_ws, size_t ws_size,
                              hipStream_t stream) {
    const float* x   = (const float*)d_in[0];
    const int*   ei  = (const int*)d_in[1];
    const int*   bat = (const int*)d_in[2];
    const float* W1  = (const float*)d_in[3];
    const float* b1  = (const float*)d_in[4];
    const float* W2  = (const float*)d_in[5];
    const float* b2  = (const float*)d_in[6];
    const float* W4  = (const float*)d_in[7];
    const float* b4  = (const float*)d_in[8];
    const float* Wd1 = (const float*)d_in[9];
    const float* bd1 = (const float*)d_in[10];
    const float* Wd2 = (const float*)d_in[11];
    const float* bd2 = (const float*)d_in[12];
    const float* Wo  = (const float*)d_in[13];
    const float* bo  = (const float*)d_in[14];
    float* out = (float*)d_out;

    const int N = in_sizes[0] / 11;
    const int E = in_sizes[1] / 2;
    const int* row = ei;
    const int* col = ei + E;
    const int B = (N + (1 << BSHIFT) - 1) >> BSHIFT;   // #buckets
    const int ngroups = (N + 15) / 16;

    size_t off = 0;
    auto carve = [&](size_t bytes) {
        void* p = (char*)d_ws + off;
        off += (bytes + 255) & ~(size_t)255;
        return p;
    };
    __half* bufHA    = (__half*)carve((size_t)N * HIDDEN * 2);
    __half* bufHB    = (__half*)carve((size_t)N * HIDDEN * 2);
    __half* xp       = (__half*)carve((size_t)N * 16 * 2);
    int*    offsets  = (int*)carve((size_t)(N + 1) * 4);
    float*  dinv     = (float*)carve((size_t)N * 4);
    int*    sorted_r = (int*)carve((size_t)E * 4);
    int*    bcnt     = (int*)carve((size_t)512 * 4);
    int*    bbase    = (int*)carve((size_t)512 * 4);
    float*  partials = (float*)carve((size_t)128 * 8 * 128 * 4);
    __half* packW2   = (__half*)carve((size_t)(32768 + 128) * 2);
    __half* packW4   = (__half*)carve((size_t)(32768 + 128) * 2);
    // ptmp aliases bufHA (dead until agg16_fused; B*BCAP*8 = 19.2 MB < 25.6 MB)
    int2* ptmp = (int2*)bufHA;
    (void)ws_size; (void)n_in; (void)out_size;

    // ---- build CSR (+ fused xp padding): bucket-binned, no global histogram
    hipMemsetAsync(bcnt, 0, (size_t)512 * 4, stream);
    fill_bin<<<(E + CHUNK - 1) / CHUNK, 256, 0, stream>>>(row, col, bcnt, ptmp, E);
    scan_buckets<<<1, 512, 0, stream>>>(bcnt, bbase, B);
    fill_scatter<<<B, 256, 0, stream>>>(ptmp, bcnt, bbase, x, offsets, dinv,
                                        sorted_r, xp, N, E);

    // ---- pack weights for MFMA (independent of CSR)
    pack_w<<<8, 256, 0, stream>>>(W2, b1, packW2);
    pack_w<<<8, 256, 0, stream>>>(W4, b2, packW4);

    int aggBlocks   = (N + 3) / 4;
    int aggSliced   = 8 * ((N + 3) / 4);

    // ---- layer 1: fused aggregate+GEMM (agg is linear; dinv folded in xp)
    agg16_fused<<<aggBlocks, 256, 0, stream>>>(xp, W1, offsets, sorted_r, dinv,
                                               bufHA, N);
    // ---- layer 2 (register-W MFMA GEMM: relu(h1+b1)@W2, dinv folded)
    gemm_mfma<<<1024, 256, 0, stream>>>(bufHA, packW2, dinv, bufHB, N, ngroups);
    agg128h_sliced<<<aggSliced, 256, 0, stream>>>(bufHB, bufHA, offsets, sorted_r,
                                                  dinv, N);
    // ---- layer 3
    gemm_mfma<<<1024, 256, 0, stream>>>(bufHA, packW4, dinv, bufHB, N, ngroups);
    agg128h_sliced<<<aggSliced, 256, 0, stream>>>(bufHB, bufHA, offsets, sorted_r,
                                                  dinv, N);
    // ---- pool + head
    pool_partial<<<128 * 8, 256, 0, stream>>>(bufHA, bat, partials, N);
    head_kernel<<<128, 128, 0, stream>>>(partials, bat, b4, Wd1, bd1, Wd2, bd2,
                                         Wo, bo, out, N);
}

// Round 14
// 361.523 us; speedup vs baseline: 1.6536x; 1.6536x over previous
//
#include <hip/hip_runtime.h>
#include <hip/hip_fp16.h>

#define HIDDEN 128
#define BSHIFT 8          // bucket = 256 destination nodes
#define BMASK 255
#define CHUNK 4096        // edges per fill_bin block (40 KB LDS -> 4 blocks/CU)
#define BCAP 6144         // per-bucket capacity in ptmp (mean 4096, 32 sigma)

// Feature buffers are SLICE-MAJOR: H[(s*N + node)*16 + c], s in [0,8), c in [0,16).
// Slice s is processed by blocks with (blockIdx&7)==s -> XCD s (round-robin
// dispatch), so each XCD's gather working set is 3.2 MB < 4 MB L2.

typedef _Float16 h8 __attribute__((ext_vector_type(8)));
typedef float f4x __attribute__((ext_vector_type(4)));

// ----------------- fill pass 1: LDS-bin edges into bucket-strided temp array
__global__ __launch_bounds__(256) void fill_bin(const int* __restrict__ row,
                                                const int* __restrict__ col,
                                                int* __restrict__ bcnt,
                                                int2* __restrict__ ptmp, int E) {
    __shared__ int cnt[512], start[512], place[512], gbase[512];
    __shared__ int ssum[256];
    __shared__ int2 stage[CHUNK];
    int t = threadIdx.x;
    int e0 = blockIdx.x * CHUNK;
    int e1 = min(e0 + CHUNK, E);
    cnt[t] = 0; cnt[t + 256] = 0;
    __syncthreads();
    for (int e = e0 + t; e < e1; e += 256)
        atomicAdd(&cnt[col[e] >> BSHIFT], 1);
    __syncthreads();
    int s2 = cnt[2 * t] + cnt[2 * t + 1];
    ssum[t] = s2;
    __syncthreads();
    for (int d = 1; d < 256; d <<= 1) {
        int v = (t >= d) ? ssum[t - d] : 0;
        __syncthreads();
        ssum[t] += v;
        __syncthreads();
    }
    int excl = ssum[t] - s2;
    start[2 * t] = excl;
    start[2 * t + 1] = excl + cnt[2 * t];
    place[2 * t] = excl;
    place[2 * t + 1] = excl + cnt[2 * t];
    __syncthreads();
    for (int e = e0 + t; e < e1; e += 256) {
        int c = col[e], r = row[e];
        int slot = atomicAdd(&place[c >> BSHIFT], 1);
        stage[slot] = make_int2(r, c);
    }
    {
        int c0 = cnt[t], c1 = cnt[t + 256];
        if (c0 > 0) gbase[t] = atomicAdd(&bcnt[t], c0);
        if (c1 > 0) gbase[t + 256] = atomicAdd(&bcnt[t + 256], c1);
    }
    __syncthreads();
    int n = e1 - e0;
    for (int i = t; i < n; i += 256) {
        int2 p = stage[i];
        int b = p.y >> BSHIFT;
        ptmp[(size_t)b * BCAP + gbase[b] + (i - start[b])] = p;
    }
}

// --------------- tiny single-block scan of bucket totals -> global CSR bases
__global__ __launch_bounds__(512) void scan_buckets(const int* __restrict__ bcnt,
                                                    int* __restrict__ bbase, int NB) {
    __shared__ int s[512];
    int t = threadIdx.x;
    int v0 = (t < NB) ? bcnt[t] : 0;
    s[t] = v0;
    __syncthreads();
    for (int d = 1; d < 512; d <<= 1) {
        int v = (t >= d) ? s[t - d] : 0;
        __syncthreads();
        s[t] += v;
        __syncthreads();
    }
    bbase[t] = s[t] - v0;   // exclusive prefix
}

// ---- fill pass 2: one block per bucket — LDS degree histogram + local scatter
// also pads this bucket's x rows into dinv-folded fp16 xp (fused pad_x)
__global__ __launch_bounds__(256) void fill_scatter(const int2* __restrict__ ptmp,
                                                    const int* __restrict__ bcnt,
                                                    const int* __restrict__ bbase,
                                                    const float* __restrict__ x,
                                                    int* __restrict__ offsets,
                                                    float* __restrict__ dinv,
                                                    int* __restrict__ sorted_r,
                                                    __half* __restrict__ xp,
                                                    int N, int E) {
    __shared__ int2 stage[BCAP];               // 48 KB
    __shared__ int cnt[256], loff[256], cur[256];
    int b = blockIdx.x, t = threadIdx.x;
    int m = bcnt[b];
    int base = bbase[b];
    int nbase = b << BSHIFT;
    cnt[t] = 0;
    __syncthreads();
    for (int i = t; i < m; i += 256) {
        int2 p = ptmp[(size_t)b * BCAP + i];
        stage[i] = p;
        atomicAdd(&cnt[p.y & BMASK], 1);
    }
    __syncthreads();
    int my = cnt[t];
    loff[t] = my;
    __syncthreads();
    for (int d = 1; d < 256; d <<= 1) {
        int v = (t >= d) ? loff[t - d] : 0;
        __syncthreads();
        loff[t] += v;
        __syncthreads();
    }
    int excl = loff[t] - my;
    cur[t] = excl;
    int node = nbase + t;
    float dv = rsqrtf((float)(my + 1));
    if (node < N) {
        offsets[node] = base + excl;
        dinv[node] = dv;
        __half hrow[16];
#pragma unroll
        for (int c = 0; c < 11; ++c)
            hrow[c] = __float2half(x[(size_t)node * 11 + c] * dv);
#pragma unroll
        for (int c = 11; c < 16; ++c) hrow[c] = __float2half(0.f);
        *(uint4*)(xp + (size_t)node * 16)     = *(uint4*)hrow;
        *(uint4*)(xp + (size_t)node * 16 + 8) = *(uint4*)(hrow + 8);
    }
    if (b == gridDim.x - 1 && t == 0) offsets[N] = E;
    __syncthreads();
    for (int i = t; i < m; i += 256) {
        int2 p = stage[i];
        int slot = atomicAdd(&cur[p.y & BMASK], 1);
        sorted_r[base + slot] = p.x;   // contiguous ~16 KB region, block-local
    }
}

// ------ agg16 + input GEMM fused: writes layer-1 H in SLICE-MAJOR fp16
__global__ __launch_bounds__(256) void agg16_fused(const __half* __restrict__ xp,
                                                   const float* __restrict__ W1,
                                                   const int* __restrict__ offsets,
                                                   const int* __restrict__ sorted_r,
                                                   const float* __restrict__ dinv,
                                                   __half* __restrict__ out, int N) {
    __shared__ float W1s[11 * 128];   // 5.6 KB
    __shared__ float arow[4][16];
    int t = threadIdx.x;
    for (int q = t; q < 11 * 128; q += 256) W1s[q] = W1[q];
    int wv = t >> 6, lane = t & 63;
    int c = blockIdx.x * 4 + wv;
    bool valid = c < N;
    int g = lane >> 3, cp = lane & 7;
    const __half2* xp2 = (const __half2*)xp;
    float ax = 0.f, ay = 0.f;
    if (valid) {
        int beg = offsets[c], end = offsets[c + 1];
        if (g == 0) {
            float2 v = __half22float2(xp2[(size_t)c * 8 + cp]);   // self (dc folded)
            ax = v.x; ay = v.y;
        }
        int i = beg;
        for (; i + 16 <= end; i += 16) {
            int r0 = sorted_r[i + g];
            int r1 = sorted_r[i + g + 8];
            float2 v0 = __half22float2(xp2[(size_t)r0 * 8 + cp]);
            float2 v1 = __half22float2(xp2[(size_t)r1 * 8 + cp]);
            ax += v0.x + v1.x; ay += v0.y + v1.y;
        }
        if (i < end) {                       // predicated batch tail
            int last = end - 1;
            int i0 = i + g, i1 = i + g + 8;
            int r0 = sorted_r[min(i0, last)];
            int r1 = sorted_r[min(i1, last)];
            float2 v0 = __half22float2(xp2[(size_t)r0 * 8 + cp]);
            float2 v1 = __half22float2(xp2[(size_t)r1 * 8 + cp]);
            if (i0 <= last) { ax += v0.x; ay += v0.y; }
            if (i1 <= last) { ax += v1.x; ay += v1.y; }
        }
    }
    ax += __shfl_xor(ax, 32); ay += __shfl_xor(ay, 32);
    ax += __shfl_xor(ax, 16); ay += __shfl_xor(ay, 16);
    ax += __shfl_xor(ax, 8);  ay += __shfl_xor(ay, 8);
    if (valid && lane < 8) {
        float dc = dinv[c];
        arow[wv][cp * 2]     = ax * dc;
        arow[wv][cp * 2 + 1] = ay * dc;
    }
    __syncthreads();
    // block GEMM: 4 nodes x 128 ch, slice-major output
    int j = t & 127, half = t >> 7;
#pragma unroll
    for (int nn = 0; nn < 2; ++nn) {
        int n = half * 2 + nn;
        int node = blockIdx.x * 4 + n;
        if (node < N) {
            float acc = 0.f;
#pragma unroll
            for (int cc = 0; cc < 11; ++cc) acc += arow[n][cc] * W1s[cc * 128 + j];
            out[((size_t)(j >> 4) * N + node) * 16 + (j & 15)] = __float2half(acc);
        }
    }
}

// ---------------- pack W [128][128] fp32 -> MFMA fragment order, hi|lo fp16
__global__ __launch_bounds__(256) void pack_w(const float* __restrict__ W,
                                              const float* __restrict__ bias,
                                              __half* __restrict__ packed) {
    int q = blockIdx.x * 256 + threadIdx.x;
    if (q < 2048) {
        int s = q >> 9, rem = q & 511, ct = rem >> 6, l = rem & 63;
        int b = l >> 4, n = l & 15;
        __half hi8[8], lo8[8];
#pragma unroll
        for (int i = 0; i < 8; ++i) {
            float w = W[(s * 32 + b * 8 + i) * HIDDEN + ct * 16 + n];
            __half h = __float2half(w);
            hi8[i] = h;
            lo8[i] = __float2half(w - __half2float(h));
        }
        *(uint4*)(packed + (size_t)q * 8)         = *(uint4*)hi8;
        *(uint4*)(packed + 16384 + (size_t)q * 8) = *(uint4*)lo8;
    }
    if (q < 128) packed[32768 + q] = __float2half(bias[q]);
}

// ---- MFMA GEMM, register-resident W; slice-major in/out
__global__ __launch_bounds__(256, 2) void gemm_mfma(const __half* __restrict__ H,
                                                    const __half* __restrict__ packed,
                                                    const float* __restrict__ dinv,
                                                    __half* __restrict__ out,
                                                    int N, int ngroups) {
    int l = threadIdx.x & 63, wv = threadIdx.x >> 6;
    int cthalf = wv & 1;
    int n16 = l & 15, koct = l >> 4;
    h8 whi[4][4], wlo[4][4];
#pragma unroll
    for (int s = 0; s < 4; ++s)
#pragma unroll
        for (int mt = 0; mt < 4; ++mt) {
            int ct = cthalf * 4 + mt;
            whi[s][mt] = *(const h8*)(packed + (size_t)((s * 8 + ct) * 64 + l) * 8);
            wlo[s][mt] = *(const h8*)(packed + 16384 + (size_t)((s * 8 + ct) * 64 + l) * 8);
        }
    h8 biasf[4];
    const __half* bias_h = packed + 32768;
#pragma unroll
    for (int s = 0; s < 4; ++s)
        biasf[s] = *(const h8*)(bias_h + s * 32 + koct * 8);

    int lsl = koct >> 1, lc0 = (koct & 1) * 8;   // load slice-part / offset

    for (int g = blockIdx.x * 2 + (wv >> 1); g < ngroups; g += gridDim.x * 2) {
        int node = g * 16 + n16;
        bool ok = node < N;
        f4x acc[4];
#pragma unroll
        for (int mt = 0; mt < 4; ++mt) acc[mt] = (f4x){0.f, 0.f, 0.f, 0.f};
#pragma unroll
        for (int s = 0; s < 4; ++s) {
            uint4 bv = make_uint4(0u, 0u, 0u, 0u);
            if (ok) {
                int sl = 2 * s + lsl;   // slice of channels k = s*32 + koct*8
                bv = *(const uint4*)(H + ((size_t)sl * N + node) * 16 + lc0);
            }
            __half2* bh2 = (__half2*)&bv;
            const __half2* bb = (const __half2*)&biasf[s];
#pragma unroll
            for (int p = 0; p < 4; ++p) {
                float2 f  = __half22float2(bh2[p]);
                float2 bf = __half22float2(bb[p]);
                bh2[p] = __floats2half2_rn(fmaxf(f.x + bf.x, 0.f), fmaxf(f.y + bf.y, 0.f));
            }
            h8 bfrag = *(h8*)&bv;
#pragma unroll
            for (int mt = 0; mt < 4; ++mt) {
                acc[mt] = __builtin_amdgcn_mfma_f32_16x16x32_f16(whi[s][mt], bfrag, acc[mt], 0, 0, 0);
                acc[mt] = __builtin_amdgcn_mfma_f32_16x16x32_f16(wlo[s][mt], bfrag, acc[mt], 0, 0, 0);
            }
        }
        if (ok) {
            float dv = dinv[node];
#pragma unroll
            for (int mt = 0; mt < 4; ++mt) {
                int sl = cthalf * 4 + mt;            // output slice
                __half2 h01 = __floats2half2_rn(acc[mt][0] * dv, acc[mt][1] * dv);
                __half2 h23 = __floats2half2_rn(acc[mt][2] * dv, acc[mt][3] * dv);
                uint2 o;
                o.x = *(unsigned int*)&h01; o.y = *(unsigned int*)&h23;
                *(uint2*)(out + ((size_t)sl * N + node) * 16 + koct * 4) = o;
            }
        }
    }
}

// -------- channel-sliced aggregation v2: slice = bid&7 -> XCD-local working set
// wave = 4 nodes x 1 slice; per node 8 edge-slots x 2 lanes x uint4 (8 ch);
// 2-phase unroll (2 outstanding gathers); 3-step shfl reduce; 16B stores.
__global__ __launch_bounds__(256) void agg128h_sliced(const __half* __restrict__ src,
                                                      __half* __restrict__ dst,
                                                      const int* __restrict__ offsets,
                                                      const int* __restrict__ sorted_r,
                                                      const float* __restrict__ dinv,
                                                      int N) {
    int s = blockIdx.x & 7;
    int t = threadIdx.x;
    int lane = t & 63, wv = t >> 6;
    int nd = lane >> 4, slot = (lane >> 1) & 7, half = lane & 1;
    int c = (blockIdx.x >> 3) * 16 + wv * 4 + nd;
    if (c >= N) return;   // reduce partners share nd-group -> co-active
    int beg = offsets[c], end = offsets[c + 1];
    const uint4* sp = (const uint4*)src + (size_t)s * N * 2;   // 2 x uint4 per row
    float a0=0.f,a1=0.f,a2=0.f,a3=0.f,a4=0.f,a5=0.f,a6=0.f,a7=0.f;
    auto accum = [&](uint4 u) {
        float2 f0 = __half22float2(*(__half2*)&u.x);
        float2 f1 = __half22float2(*(__half2*)&u.y);
        float2 f2 = __half22float2(*(__half2*)&u.z);
        float2 f3 = __half22float2(*(__half2*)&u.w);
        a0 += f0.x; a1 += f0.y; a2 += f1.x; a3 += f1.y;
        a4 += f2.x; a5 += f2.y; a6 += f3.x; a7 += f3.y;
    };
    if (slot == 0) accum(sp[(size_t)c * 2 + half]);   // self loop (dinv folded)
    int i = beg;
    for (; i + 16 <= end; i += 16) {                  // 2 phases in flight
        int r0 = sorted_r[i + slot];
        int r1 = sorted_r[i + 8 + slot];
        uint4 u0 = sp[(size_t)r0 * 2 + half];
        uint4 u1 = sp[(size_t)r1 * 2 + half];
        accum(u0); accum(u1);
    }
    for (; i + 8 <= end; i += 8) {
        int r = sorted_r[i + slot];
        accum(sp[(size_t)r * 2 + half]);
    }
    if (i < end) {                                    // predicated batch tail
        int last = end - 1;
        int ii = i + slot;
        int r = sorted_r[min(ii, last)];
        uint4 u = sp[(size_t)r * 2 + half];
        if (ii <= last) accum(u);
    }
    // reduce over the 8 edge-slots (lane bits 1..3)
    a0 += __shfl_xor(a0, 2); a1 += __shfl_xor(a1, 2);
    a2 += __shfl_xor(a2, 2); a3 += __shfl_xor(a3, 2);
    a4 += __shfl_xor(a4, 2); a5 += __shfl_xor(a5, 2);
    a6 += __shfl_xor(a6, 2); a7 += __shfl_xor(a7, 2);
    a0 += __shfl_xor(a0, 4); a1 += __shfl_xor(a1, 4);
    a2 += __shfl_xor(a2, 4); a3 += __shfl_xor(a3, 4);
    a4 += __shfl_xor(a4, 4); a5 += __shfl_xor(a5, 4);
    a6 += __shfl_xor(a6, 4); a7 += __shfl_xor(a7, 4);
    a0 += __shfl_xor(a0, 8); a1 += __shfl_xor(a1, 8);
    a2 += __shfl_xor(a2, 8); a3 += __shfl_xor(a3, 8);
    a4 += __shfl_xor(a4, 8); a5 += __shfl_xor(a5, 8);
    a6 += __shfl_xor(a6, 8); a7 += __shfl_xor(a7, 8);
    if (slot == 0) {
        float dc = dinv[c];
        __half2 h01 = __floats2half2_rn(a0 * dc, a1 * dc);
        __half2 h23 = __floats2half2_rn(a2 * dc, a3 * dc);
        __half2 h45 = __floats2half2_rn(a4 * dc, a5 * dc);
        __half2 h67 = __floats2half2_rn(a6 * dc, a7 * dc);
        uint4 o;
        o.x = *(unsigned int*)&h01; o.y = *(unsigned int*)&h23;
        o.z = *(unsigned int*)&h45; o.w = *(unsigned int*)&h67;
        ((uint4*)dst + (size_t)s * N * 2)[(size_t)c * 2 + half] = o;
    }
}

// --------------------------------------------- pooling stage 1 (slice-major in)
__global__ __launch_bounds__(256) void pool_partial(const __half* __restrict__ h,
                                                    const int* __restrict__ batch,
                                                    float* __restrict__ partials, int N) {
    int g = blockIdx.x >> 3, part8 = blockIdx.x & 7;
    int t = threadIdx.x, cp = t & 63, rp = t >> 6;
    int lo = 0, hi = N;
    while (lo < hi) { int m = (lo + hi) >> 1; if (batch[m] < g) lo = m + 1; else hi = m; }
    int beg = lo;
    lo = beg; hi = N;
    while (lo < hi) { int m = (lo + hi) >> 1; if (batch[m] < g + 1) lo = m + 1; else hi = m; }
    int end = lo;
    const __half2* h2 = (const __half2*)h;
    size_t sbase = (size_t)(cp >> 3) * N * 8;   // slice of channel-pair cp
    int soff = cp & 7;
    float ax = 0.f, ay = 0.f;
    for (int i = beg + part8 * 4 + rp; i < end; i += 32) {
        float2 v = __half22float2(h2[sbase + (size_t)i * 8 + soff]);
        ax += v.x; ay += v.y;
    }
    __shared__ float px[4][64], py[4][64];
    px[rp][cp] = ax; py[rp][cp] = ay;
    __syncthreads();
    if (rp == 0) {
        float sx = px[0][cp] + px[1][cp] + px[2][cp] + px[3][cp];
        float sy = py[0][cp] + py[1][cp] + py[2][cp] + py[3][cp];
        partials[(size_t)blockIdx.x * 128 + cp * 2]     = sx;
        partials[(size_t)blockIdx.x * 128 + cp * 2 + 1] = sy;
    }
}

// ------------------------------------------------- pooling stage 2 + MLP head
__global__ __launch_bounds__(128) void head_kernel(const float* __restrict__ partials,
                                                   const int* __restrict__ batch,
                                                   const float* __restrict__ b4,
                                                   const float* __restrict__ Wd1,
                                                   const float* __restrict__ bd1,
                                                   const float* __restrict__ Wd2,
                                                   const float* __restrict__ bd2,
                                                   const float* __restrict__ Wo,
                                                   const float* __restrict__ bo,
                                                   float* __restrict__ out, int N) {
    int g = blockIdx.x;
    int j = threadIdx.x;
    __shared__ float sA[128], sB[128], red[128];
    int lo = 0, hi = N;
    while (lo < hi) { int m = (lo + hi) >> 1; if (batch[m] < g) lo = m + 1; else hi = m; }
    int beg = lo;
    lo = beg; hi = N;
    while (lo < hi) { int m = (lo + hi) >> 1; if (batch[m] < g + 1) lo = m + 1; else hi = m; }
    int cnt = lo - beg;
    float s = 0.f;
#pragma unroll
    for (int p = 0; p < 8; ++p) s += partials[(size_t)(g * 8 + p) * 128 + j];
    sA[j] = (cnt > 0) ? s / (float)cnt + b4[j] : 0.f;
    __syncthreads();
    float a = bd1[j];
#pragma unroll 4
    for (int k = 0; k < 128; ++k) a += sA[k] * Wd1[k * HIDDEN + j];
    sB[j] = fmaxf(a, 0.f);
    __syncthreads();
    a = bd2[j];
#pragma unroll 4
    for (int k = 0; k < 128; ++k) a += sB[k] * Wd2[k * HIDDEN + j];
    red[j] = fmaxf(a, 0.f) * Wo[j];
    __syncthreads();
    for (int d = 64; d > 0; d >>= 1) {
        if (j < d) red[j] += red[j + d];
        __syncthreads();
    }
    if (j == 0) out[g] = red[0] + bo[0];
}

// ============================================================================
extern "C" void kernel_launch(void* const* d_in, const int* in_sizes, int n_in,
                              void* d_out, int out_size, void* d_ws, size_t ws_size,
                              hipStream_t stream) {
    const float* x   = (const float*)d_in[0];
    const int*   ei  = (const int*)d_in[1];
    const int*   bat = (const int*)d_in[2];
    const float* W1  = (const float*)d_in[3];
    const float* b1  = (const float*)d_in[4];
    const float* W2  = (const float*)d_in[5];
    const float* b2  = (const float*)d_in[6];
    const float* W4  = (const float*)d_in[7];
    const float* b4  = (const float*)d_in[8];
    const float* Wd1 = (const float*)d_in[9];
    const float* bd1 = (const float*)d_in[10];
    const float* Wd2 = (const float*)d_in[11];
    const float* bd2 = (const float*)d_in[12];
    const float* Wo  = (const float*)d_in[13];
    const float* bo  = (const float*)d_in[14];
    float* out = (float*)d_out;

    const int N = in_sizes[0] / 11;
    const int E = in_sizes[1] / 2;
    const int* row = ei;
    const int* col = ei + E;
    const int B = (N + (1 << BSHIFT) - 1) >> BSHIFT;   // #buckets
    const int ngroups = (N + 15) / 16;

    size_t off = 0;
    auto carve = [&](size_t bytes) {
        void* p = (char*)d_ws + off;
        off += (bytes + 255) & ~(size_t)255;
        return p;
    };
    __half* bufHA    = (__half*)carve((size_t)N * HIDDEN * 2);
    __half* bufHB    = (__half*)carve((size_t)N * HIDDEN * 2);
    __half* xp       = (__half*)carve((size_t)N * 16 * 2);
    int*    offsets  = (int*)carve((size_t)(N + 1) * 4);
    float*  dinv     = (float*)carve((size_t)N * 4);
    int*    sorted_r = (int*)carve((size_t)E * 4);
    int*    bcnt     = (int*)carve((size_t)512 * 4);
    int*    bbase    = (int*)carve((size_t)512 * 4);
    float*  partials = (float*)carve((size_t)128 * 8 * 128 * 4);
    __half* packW2   = (__half*)carve((size_t)(32768 + 128) * 2);
    __half* packW4   = (__half*)carve((size_t)(32768 + 128) * 2);
    // ptmp aliases bufHA (dead until agg16_fused; B*BCAP*8 = 19.2 MB < 25.6 MB)
    int2* ptmp = (int2*)bufHA;
    (void)ws_size; (void)n_in; (void)out_size;

    // ---- build CSR (+ fused xp padding): bucket-binned, no global histogram
    hipMemsetAsync(bcnt, 0, (size_t)512 * 4, stream);
    fill_bin<<<(E + CHUNK - 1) / CHUNK, 256, 0, stream>>>(row, col, bcnt, ptmp, E);
    scan_buckets<<<1, 512, 0, stream>>>(bcnt, bbase, B);
    fill_scatter<<<B, 256, 0, stream>>>(ptmp, bcnt, bbase, x, offsets, dinv,
                                        sorted_r, xp, N, E);

    // ---- pack weights for MFMA (independent of CSR)
    pack_w<<<8, 256, 0, stream>>>(W2, b1, packW2);
    pack_w<<<8, 256, 0, stream>>>(W4, b2, packW4);

    int aggBlocks   = (N + 3) / 4;
    int aggSliced   = 8 * ((N + 15) / 16);

    // ---- layer 1: fused aggregate+GEMM (agg is linear; dinv folded in xp)
    agg16_fused<<<aggBlocks, 256, 0, stream>>>(xp, W1, offsets, sorted_r, dinv,
                                               bufHA, N);
    // ---- layer 2 (register-W MFMA GEMM: relu(h1+b1)@W2, dinv folded)
    gemm_mfma<<<1024, 256, 0, stream>>>(bufHA, packW2, dinv, bufHB, N, ngroups);
    agg128h_sliced<<<aggSliced, 256, 0, stream>>>(bufHB, bufHA, offsets, sorted_r,
                                                  dinv, N);
    // ---- layer 3
    gemm_mfma<<<1024, 256, 0, stream>>>(bufHA, packW4, dinv, bufHB, N, ngroups);
    agg128h_sliced<<<aggSliced, 256, 0, stream>>>(bufHB, bufHA, offsets, sorted_r,
                                                  dinv, N);
    // ---- pool + head
    pool_partial<<<128 * 8, 256, 0, stream>>>(bufHA, bat, partials, N);
    head_kernel<<<128, 128, 0, stream>>>(partials, bat, b4, Wd1, bd1, Wd2, bd2,
                                         Wo, bo, out, N);
}

// Round 15
// 314.312 us; speedup vs baseline: 1.9020x; 1.1502x over previous
//
#include <hip/hip_runtime.h>
#include <hip/hip_fp16.h>

#define HIDDEN 128
#define BSHIFT 8          // bucket = 256 destination nodes
#define BMASK 255
#define CHUNK 8192        // edges per fill_bin block (32KB stage + 9KB ctrs)
#define BCAP 6144         // per-bucket capacity in ptmp (mean 4096, 32 sigma)

typedef _Float16 h8 __attribute__((ext_vector_type(8)));
typedef float f4x __attribute__((ext_vector_type(4)));

// ---- fill pass 1: LDS-bin edges into bucket-strided temp array (packed 4B)
// packed entry = (r << 8) | (c & 255); bucket = c >> 8 (r < 2^24)
__global__ __launch_bounds__(256) void fill_bin(const int* __restrict__ row,
                                                const int* __restrict__ col,
                                                int* __restrict__ bcnt,
                                                unsigned* __restrict__ ptmp, int E) {
    __shared__ int cnt[512], start[512], place[512], gbase[512];
    __shared__ int ssum[256];
    __shared__ unsigned stage[CHUNK];          // 32 KB
    int t = threadIdx.x;
    int e0 = blockIdx.x * CHUNK;
    int e1 = min(e0 + CHUNK, E);
    cnt[t] = 0; cnt[t + 256] = 0;
    __syncthreads();
    for (int e = e0 + t; e < e1; e += 256)
        atomicAdd(&cnt[col[e] >> BSHIFT], 1);
    __syncthreads();
    int s2 = cnt[2 * t] + cnt[2 * t + 1];
    ssum[t] = s2;
    __syncthreads();
    for (int d = 1; d < 256; d <<= 1) {
        int v = (t >= d) ? ssum[t - d] : 0;
        __syncthreads();
        ssum[t] += v;
        __syncthreads();
    }
    int excl = ssum[t] - s2;
    start[2 * t] = excl;
    start[2 * t + 1] = excl + cnt[2 * t];
    place[2 * t] = excl;
    place[2 * t + 1] = excl + cnt[2 * t];
    __syncthreads();
    for (int e = e0 + t; e < e1; e += 256) {
        int c = col[e], r = row[e];
        int slot = atomicAdd(&place[c >> BSHIFT], 1);
        stage[slot] = ((unsigned)r << 8) | (unsigned)(c & BMASK);
    }
    {
        int c0 = cnt[t], c1 = cnt[t + 256];
        if (c0 > 0) gbase[t] = atomicAdd(&bcnt[t], c0);
        if (c1 > 0) gbase[t + 256] = atomicAdd(&bcnt[t + 256], c1);
    }
    __syncthreads();
    // stream out: each thread owns buckets t and t+256; bucket runs contiguous
    for (int bb = t; bb < 512; bb += 256) {
        int n = cnt[bb];
        if (n > 0) {
            int st = start[bb], gb = gbase[bb];
            unsigned* dst = ptmp + (size_t)bb * BCAP + gb;
            for (int k = 0; k < n; ++k) dst[k] = stage[st + k];
        }
    }
}

// --------------- tiny single-block scan of bucket totals -> global CSR bases
__global__ __launch_bounds__(512) void scan_buckets(const int* __restrict__ bcnt,
                                                    int* __restrict__ bbase, int NB) {
    __shared__ int s[512];
    int t = threadIdx.x;
    int v0 = (t < NB) ? bcnt[t] : 0;
    s[t] = v0;
    __syncthreads();
    for (int d = 1; d < 512; d <<= 1) {
        int v = (t >= d) ? s[t - d] : 0;
        __syncthreads();
        s[t] += v;
        __syncthreads();
    }
    bbase[t] = s[t] - v0;   // exclusive prefix
}

// ---- fill pass 2: one block per bucket — LDS degree histogram + local scatter
// also pads this bucket's x rows into dinv-folded fp16 xp (fused pad_x)
__global__ __launch_bounds__(256) void fill_scatter(const unsigned* __restrict__ ptmp,
                                                    const int* __restrict__ bcnt,
                                                    const int* __restrict__ bbase,
                                                    const float* __restrict__ x,
                                                    int* __restrict__ offsets,
                                                    float* __restrict__ dinv,
                                                    int* __restrict__ sorted_r,
                                                    __half* __restrict__ xp,
                                                    int N, int E) {
    __shared__ unsigned stage[BCAP];           // 24 KB
    __shared__ int cnt[256], loff[256], cur[256];
    int b = blockIdx.x, t = threadIdx.x;
    int m = bcnt[b];
    int base = bbase[b];
    int nbase = b << BSHIFT;
    cnt[t] = 0;
    __syncthreads();
    for (int i = t; i < m; i += 256) {
        unsigned p = ptmp[(size_t)b * BCAP + i];
        stage[i] = p;
        atomicAdd(&cnt[p & BMASK], 1);
    }
    __syncthreads();
    int my = cnt[t];
    loff[t] = my;
    __syncthreads();
    for (int d = 1; d < 256; d <<= 1) {
        int v = (t >= d) ? loff[t - d] : 0;
        __syncthreads();
        loff[t] += v;
        __syncthreads();
    }
    int excl = loff[t] - my;
    cur[t] = excl;
    int node = nbase + t;
    float dv = rsqrtf((float)(my + 1));
    if (node < N) {
        offsets[node] = base + excl;
        dinv[node] = dv;
        __half hrow[16];
#pragma unroll
        for (int c = 0; c < 11; ++c)
            hrow[c] = __float2half(x[(size_t)node * 11 + c] * dv);
#pragma unroll
        for (int c = 11; c < 16; ++c) hrow[c] = __float2half(0.f);
        *(uint4*)(xp + (size_t)node * 16)     = *(uint4*)hrow;
        *(uint4*)(xp + (size_t)node * 16 + 8) = *(uint4*)(hrow + 8);
    }
    if (b == gridDim.x - 1 && t == 0) offsets[N] = E;
    __syncthreads();
    for (int i = t; i < m; i += 256) {
        unsigned p = stage[i];
        int slot = atomicAdd(&cur[p & BMASK], 1);
        sorted_r[base + slot] = (int)(p >> 8);   // block-local ~16 KB region
    }
}

// ------ agg16 + input GEMM fused: bufHA[c] = fp16( (dc*(sum+self))[:11] @ W1 )
__global__ __launch_bounds__(256) void agg16_fused(const __half* __restrict__ xp,
                                                   const float* __restrict__ W1,
                                                   const int* __restrict__ offsets,
                                                   const int* __restrict__ sorted_r,
                                                   const float* __restrict__ dinv,
                                                   __half* __restrict__ out, int N) {
    __shared__ float W1s[11 * 128];   // 5.6 KB
    __shared__ float arow[4][16];
    int t = threadIdx.x;
    for (int q = t; q < 11 * 128; q += 256) W1s[q] = W1[q];
    int wv = t >> 6, lane = t & 63;
    int c = blockIdx.x * 4 + wv;
    bool valid = c < N;
    int g = lane >> 3, cp = lane & 7;
    const __half2* xp2 = (const __half2*)xp;
    float ax = 0.f, ay = 0.f;
    if (valid) {
        int beg = offsets[c], end = offsets[c + 1];
        if (g == 0) {
            float2 v = __half22float2(xp2[(size_t)c * 8 + cp]);   // self (dc folded)
            ax = v.x; ay = v.y;
        }
        int i = beg;
        for (; i + 16 <= end; i += 16) {
            int r0 = sorted_r[i + g];
            int r1 = sorted_r[i + g + 8];
            float2 v0 = __half22float2(xp2[(size_t)r0 * 8 + cp]);
            float2 v1 = __half22float2(xp2[(size_t)r1 * 8 + cp]);
            ax += v0.x + v1.x; ay += v0.y + v1.y;
        }
        if (i < end) {                       // predicated batch tail
            int last = end - 1;
            int i0 = i + g, i1 = i + g + 8;
            int r0 = sorted_r[min(i0, last)];
            int r1 = sorted_r[min(i1, last)];
            float2 v0 = __half22float2(xp2[(size_t)r0 * 8 + cp]);
            float2 v1 = __half22float2(xp2[(size_t)r1 * 8 + cp]);
            if (i0 <= last) { ax += v0.x; ay += v0.y; }
            if (i1 <= last) { ax += v1.x; ay += v1.y; }
        }
    }
    ax += __shfl_xor(ax, 32); ay += __shfl_xor(ay, 32);
    ax += __shfl_xor(ax, 16); ay += __shfl_xor(ay, 16);
    ax += __shfl_xor(ax, 8);  ay += __shfl_xor(ay, 8);
    if (valid && lane < 8) {
        float dc = dinv[c];
        arow[wv][cp * 2]     = ax * dc;
        arow[wv][cp * 2 + 1] = ay * dc;
    }
    __syncthreads();
    int j = t & 127, half = t >> 7;
#pragma unroll
    for (int nn = 0; nn < 2; ++nn) {
        int n = half * 2 + nn;
        int node = blockIdx.x * 4 + n;
        if (node < N) {
            float acc = 0.f;
#pragma unroll
            for (int cc = 0; cc < 11; ++cc) acc += arow[n][cc] * W1s[cc * 128 + j];
            out[(size_t)node * HIDDEN + j] = __float2half(acc);
        }
    }
}

// ---------------- pack W [128][128] fp32 -> MFMA fragment order, hi|lo fp16
__global__ __launch_bounds__(256) void pack_w(const float* __restrict__ W,
                                              const float* __restrict__ bias,
                                              __half* __restrict__ packed) {
    int q = blockIdx.x * 256 + threadIdx.x;
    if (q < 2048) {
        int s = q >> 9, rem = q & 511, ct = rem >> 6, l = rem & 63;
        int b = l >> 4, n = l & 15;
        __half hi8[8], lo8[8];
#pragma unroll
        for (int i = 0; i < 8; ++i) {
            float w = W[(s * 32 + b * 8 + i) * HIDDEN + ct * 16 + n];
            __half h = __float2half(w);
            hi8[i] = h;
            lo8[i] = __float2half(w - __half2float(h));
        }
        *(uint4*)(packed + (size_t)q * 8)         = *(uint4*)hi8;
        *(uint4*)(packed + 16384 + (size_t)q * 8) = *(uint4*)lo8;
    }
    if (q < 128) packed[32768 + q] = __float2half(bias[q]);
}

// ---- MFMA GEMM, register-resident W (swapped operands, no LDS); row-major
__global__ __launch_bounds__(256, 2) void gemm_mfma(const __half* __restrict__ H,
                                                    const __half* __restrict__ packed,
                                                    const float* __restrict__ dinv,
                                                    __half* __restrict__ out,
                                                    int N, int ngroups) {
    int l = threadIdx.x & 63, wv = threadIdx.x >> 6;
    int cthalf = wv & 1;
    int n16 = l & 15, koct = l >> 4;
    h8 whi[4][4], wlo[4][4];
#pragma unroll
    for (int s = 0; s < 4; ++s)
#pragma unroll
        for (int mt = 0; mt < 4; ++mt) {
            int ct = cthalf * 4 + mt;
            whi[s][mt] = *(const h8*)(packed + (size_t)((s * 8 + ct) * 64 + l) * 8);
            wlo[s][mt] = *(const h8*)(packed + 16384 + (size_t)((s * 8 + ct) * 64 + l) * 8);
        }
    h8 biasf[4];
    const __half* bias_h = packed + 32768;
#pragma unroll
    for (int s = 0; s < 4; ++s)
        biasf[s] = *(const h8*)(bias_h + s * 32 + koct * 8);

    for (int g = blockIdx.x * 2 + (wv >> 1); g < ngroups; g += gridDim.x * 2) {
        int node = g * 16 + n16;
        bool ok = node < N;
        f4x acc[4];
#pragma unroll
        for (int mt = 0; mt < 4; ++mt) acc[mt] = (f4x){0.f, 0.f, 0.f, 0.f};
#pragma unroll
        for (int s = 0; s < 4; ++s) {
            uint4 bv = make_uint4(0u, 0u, 0u, 0u);
            if (ok) bv = *(const uint4*)(H + (size_t)node * HIDDEN + s * 32 + koct * 8);
            __half2* bh2 = (__half2*)&bv;
            const __half2* bb = (const __half2*)&biasf[s];
#pragma unroll
            for (int p = 0; p < 4; ++p) {
                float2 f  = __half22float2(bh2[p]);
                float2 bf = __half22float2(bb[p]);
                bh2[p] = __floats2half2_rn(fmaxf(f.x + bf.x, 0.f), fmaxf(f.y + bf.y, 0.f));
            }
            h8 bfrag = *(h8*)&bv;
#pragma unroll
            for (int mt = 0; mt < 4; ++mt) {
                acc[mt] = __builtin_amdgcn_mfma_f32_16x16x32_f16(whi[s][mt], bfrag, acc[mt], 0, 0, 0);
                acc[mt] = __builtin_amdgcn_mfma_f32_16x16x32_f16(wlo[s][mt], bfrag, acc[mt], 0, 0, 0);
            }
        }
        if (ok) {
            float dv = dinv[node];
#pragma unroll
            for (int mt = 0; mt < 4; ++mt) {
                int ch = (cthalf * 4 + mt) * 16 + koct * 4;
                __half2 h01 = __floats2half2_rn(acc[mt][0] * dv, acc[mt][1] * dv);
                __half2 h23 = __floats2half2_rn(acc[mt][2] * dv, acc[mt][3] * dv);
                uint2 o;
                o.x = *(unsigned int*)&h01; o.y = *(unsigned int*)&h23;
                *(uint2*)(out + (size_t)node * HIDDEN + ch) = o;
            }
        }
    }
}

// -------- aggregation 128ch fp16 (round-12 geometry: wave=node, 4 groups x16)
__global__ __launch_bounds__(256) void agg128h(const __half* __restrict__ src,
                                               __half* __restrict__ dst,
                                               const int* __restrict__ offsets,
                                               const int* __restrict__ sorted_r,
                                               const float* __restrict__ dinv, int N) {
    int wid  = (blockIdx.x * 256 + threadIdx.x) >> 6;
    int lane = threadIdx.x & 63;
    if (wid >= N) return;
    int c = wid;
    int beg = offsets[c], end = offsets[c + 1];
    int g = lane >> 4, sub = lane & 15;
    const uint4* hp = (const uint4*)src;
    float a0=0.f,a1=0.f,a2=0.f,a3=0.f,a4=0.f,a5=0.f,a6=0.f,a7=0.f;

    auto accum = [&](uint4 u) {
        float2 f0 = __half22float2(*(__half2*)&u.x);
        float2 f1 = __half22float2(*(__half2*)&u.y);
        float2 f2 = __half22float2(*(__half2*)&u.z);
        float2 f3 = __half22float2(*(__half2*)&u.w);
        a0 += f0.x; a1 += f0.y; a2 += f1.x; a3 += f1.y;
        a4 += f2.x; a5 += f2.y; a6 += f3.x; a7 += f3.y;
    };

    if (g == 0) accum(hp[(size_t)c * 16 + sub]);   // self loop (dinv folded)

    int i = beg;
    for (; i + 16 <= end; i += 16) {
        int base = i + 4 * g;
        int r0 = sorted_r[base + 0];
        int r1 = sorted_r[base + 1];
        int r2 = sorted_r[base + 2];
        int r3 = sorted_r[base + 3];
        uint4 u0 = hp[(size_t)r0 * 16 + sub];
        uint4 u1 = hp[(size_t)r1 * 16 + sub];
        uint4 u2 = hp[(size_t)r2 * 16 + sub];
        uint4 u3 = hp[(size_t)r3 * 16 + sub];
        accum(u0); accum(u1); accum(u2); accum(u3);
    }
    if (i < end) {                                 // predicated batch tail
        int last = end - 1;
        int i0 = i + 4 * g, i1 = i0 + 1, i2 = i0 + 2, i3 = i0 + 3;
        int r0 = sorted_r[min(i0, last)];
        int r1 = sorted_r[min(i1, last)];
        int r2 = sorted_r[min(i2, last)];
        int r3 = sorted_r[min(i3, last)];
        uint4 u0 = hp[(size_t)r0 * 16 + sub];
        uint4 u1 = hp[(size_t)r1 * 16 + sub];
        uint4 u2 = hp[(size_t)r2 * 16 + sub];
        uint4 u3 = hp[(size_t)r3 * 16 + sub];
        if (i0 <= last) accum(u0);
        if (i1 <= last) accum(u1);
        if (i2 <= last) accum(u2);
        if (i3 <= last) accum(u3);
    }
    a0 += __shfl_xor(a0, 32); a1 += __shfl_xor(a1, 32);
    a2 += __shfl_xor(a2, 32); a3 += __shfl_xor(a3, 32);
    a4 += __shfl_xor(a4, 32); a5 += __shfl_xor(a5, 32);
    a6 += __shfl_xor(a6, 32); a7 += __shfl_xor(a7, 32);
    a0 += __shfl_xor(a0, 16); a1 += __shfl_xor(a1, 16);
    a2 += __shfl_xor(a2, 16); a3 += __shfl_xor(a3, 16);
    a4 += __shfl_xor(a4, 16); a5 += __shfl_xor(a5, 16);
    a6 += __shfl_xor(a6, 16); a7 += __shfl_xor(a7, 16);
    if (g == 0) {
        float dc = dinv[c];
        __half2 h01 = __floats2half2_rn(a0 * dc, a1 * dc);
        __half2 h23 = __floats2half2_rn(a2 * dc, a3 * dc);
        __half2 h45 = __floats2half2_rn(a4 * dc, a5 * dc);
        __half2 h67 = __floats2half2_rn(a6 * dc, a7 * dc);
        uint4 o;
        o.x = *(unsigned int*)&h01; o.y = *(unsigned int*)&h23;
        o.z = *(unsigned int*)&h45; o.w = *(unsigned int*)&h67;
        ((uint4*)dst)[(size_t)c * 16 + sub] = o;
    }
}

// --------------------------------------------- pooling stage 1: partial sums
__global__ __launch_bounds__(256) void pool_partial(const __half* __restrict__ h,
                                                    const int* __restrict__ batch,
                                                    float* __restrict__ partials, int N) {
    int g = blockIdx.x >> 3, part8 = blockIdx.x & 7;
    int t = threadIdx.x, cp = t & 63, rp = t >> 6;
    int lo = 0, hi = N;
    while (lo < hi) { int m = (lo + hi) >> 1; if (batch[m] < g) lo = m + 1; else hi = m; }
    int beg = lo;
    lo = beg; hi = N;
    while (lo < hi) { int m = (lo + hi) >> 1; if (batch[m] < g + 1) lo = m + 1; else hi = m; }
    int end = lo;
    const __half2* h2 = (const __half2*)h;
    float ax = 0.f, ay = 0.f;
    for (int i = beg + part8 * 4 + rp; i < end; i += 32) {
        float2 v = __half22float2(h2[(size_t)i * 64 + cp]);
        ax += v.x; ay += v.y;
    }
    __shared__ float px[4][64], py[4][64];
    px[rp][cp] = ax; py[rp][cp] = ay;
    __syncthreads();
    if (rp == 0) {
        float sx = px[0][cp] + px[1][cp] + px[2][cp] + px[3][cp];
        float sy = py[0][cp] + py[1][cp] + py[2][cp] + py[3][cp];
        partials[(size_t)blockIdx.x * 128 + cp * 2]     = sx;
        partials[(size_t)blockIdx.x * 128 + cp * 2 + 1] = sy;
    }
}

// ------------------------------------------------- pooling stage 2 + MLP head
__global__ __launch_bounds__(128) void head_kernel(const float* __restrict__ partials,
                                                   const int* __restrict__ batch,
                                                   const float* __restrict__ b4,
                                                   const float* __restrict__ Wd1,
                                                   const float* __restrict__ bd1,
                                                   const float* __restrict__ Wd2,
                                                   const float* __restrict__ bd2,
                                                   const float* __restrict__ Wo,
                                                   const float* __restrict__ bo,
                                                   float* __restrict__ out, int N) {
    int g = blockIdx.x;
    int j = threadIdx.x;
    __shared__ float sA[128], sB[128], red[128];
    int lo = 0, hi = N;
    while (lo < hi) { int m = (lo + hi) >> 1; if (batch[m] < g) lo = m + 1; else hi = m; }
    int beg = lo;
    lo = beg; hi = N;
    while (lo < hi) { int m = (lo + hi) >> 1; if (batch[m] < g + 1) lo = m + 1; else hi = m; }
    int cnt = lo - beg;
    float s = 0.f;
#pragma unroll
    for (int p = 0; p < 8; ++p) s += partials[(size_t)(g * 8 + p) * 128 + j];
    sA[j] = (cnt > 0) ? s / (float)cnt + b4[j] : 0.f;
    __syncthreads();
    float a = bd1[j];
#pragma unroll 4
    for (int k = 0; k < 128; ++k) a += sA[k] * Wd1[k * HIDDEN + j];
    sB[j] = fmaxf(a, 0.f);
    __syncthreads();
    a = bd2[j];
#pragma unroll 4
    for (int k = 0; k < 128; ++k) a += sB[k] * Wd2[k * HIDDEN + j];
    red[j] = fmaxf(a, 0.f) * Wo[j];
    __syncthreads();
    for (int d = 64; d > 0; d >>= 1) {
        if (j < d) red[j] += red[j + d];
        __syncthreads();
    }
    if (j == 0) out[g] = red[0] + bo[0];
}

// ============================================================================
extern "C" void kernel_launch(void* const* d_in, const int* in_sizes, int n_in,
                              void* d_out, int out_size, void* d_ws, size_t ws_size,
                              hipStream_t stream) {
    const float* x   = (const float*)d_in[0];
    const int*   ei  = (const int*)d_in[1];
    const int*   bat = (const int*)d_in[2];
    const float* W1  = (const float*)d_in[3];
    const float* b1  = (const float*)d_in[4];
    const float* W2  = (const float*)d_in[5];
    const float* b2  = (const float*)d_in[6];
    const float* W4  = (const float*)d_in[7];
    const float* b4  = (const float*)d_in[8];
    const float* Wd1 = (const float*)d_in[9];
    const float* bd1 = (const float*)d_in[10];
    const float* Wd2 = (const float*)d_in[11];
    const float* bd2 = (const float*)d_in[12];
    const float* Wo  = (const float*)d_in[13];
    const float* bo  = (const float*)d_in[14];
    float* out = (float*)d_out;

    const int N = in_sizes[0] / 11;
    const int E = in_sizes[1] / 2;
    const int* row = ei;
    const int* col = ei + E;
    const int B = (N + (1 << BSHIFT) - 1) >> BSHIFT;   // #buckets
    const int ngroups = (N + 15) / 16;

    size_t off = 0;
    auto carve = [&](size_t bytes) {
        void* p = (char*)d_ws + off;
        off += (bytes + 255) & ~(size_t)255;
        return p;
    };
    __half* bufHA    = (__half*)carve((size_t)N * HIDDEN * 2);
    __half* bufHB    = (__half*)carve((size_t)N * HIDDEN * 2);
    __half* xp       = (__half*)carve((size_t)N * 16 * 2);
    int*    offsets  = (int*)carve((size_t)(N + 1) * 4);
    float*  dinv     = (float*)carve((size_t)N * 4);
    int*    sorted_r = (int*)carve((size_t)E * 4);
    int*    bcnt     = (int*)carve((size_t)512 * 4);
    int*    bbase    = (int*)carve((size_t)512 * 4);
    float*  partials = (float*)carve((size_t)128 * 8 * 128 * 4);
    __half* packW2   = (__half*)carve((size_t)(32768 + 128) * 2);
    __half* packW4   = (__half*)carve((size_t)(32768 + 128) * 2);
    // ptmp aliases bufHA (dead until agg16_fused; B*BCAP*4 = 9.6 MB < 25.6 MB)
    unsigned* ptmp = (unsigned*)bufHA;
    (void)ws_size; (void)n_in; (void)out_size;

    // ---- build CSR (+ fused xp padding): bucket-binned, no global histogram
    hipMemsetAsync(bcnt, 0, (size_t)512 * 4, stream);
    fill_bin<<<(E + CHUNK - 1) / CHUNK, 256, 0, stream>>>(row, col, bcnt, ptmp, E);
    scan_buckets<<<1, 512, 0, stream>>>(bcnt, bbase, B);
    fill_scatter<<<B, 256, 0, stream>>>(ptmp, bcnt, bbase, x, offsets, dinv,
                                        sorted_r, xp, N, E);

    // ---- pack weights for MFMA (independent of CSR)
    pack_w<<<8, 256, 0, stream>>>(W2, b1, packW2);
    pack_w<<<8, 256, 0, stream>>>(W4, b2, packW4);

    int aggBlocks = (N + 3) / 4;

    // ---- layer 1: fused aggregate+GEMM (agg is linear; dinv folded in xp)
    agg16_fused<<<aggBlocks, 256, 0, stream>>>(xp, W1, offsets, sorted_r, dinv,
                                               bufHA, N);
    // ---- layer 2 (register-W MFMA GEMM: relu(h1+b1)@W2, dinv folded)
    gemm_mfma<<<1024, 256, 0, stream>>>(bufHA, packW2, dinv, bufHB, N, ngroups);
    agg128h<<<aggBlocks, 256, 0, stream>>>(bufHB, bufHA, offsets, sorted_r, dinv, N);
    // ---- layer 3
    gemm_mfma<<<1024, 256, 0, stream>>>(bufHA, packW4, dinv, bufHB, N, ngroups);
    agg128h<<<aggBlocks, 256, 0, stream>>>(bufHB, bufHA, offsets, sorted_r, dinv, N);
    // ---- pool + head
    pool_partial<<<128 * 8, 256, 0, stream>>>(bufHA, bat, partials, N);
    head_kernel<<<128, 128, 0, stream>>>(partials, bat, b4, Wd1, bd1, Wd2, bd2,
                                         Wo, bo, out, N);
}